// Round 1
// baseline (678.446 us; speedup 1.0000x reference)
//
#include <hip/hip_runtime.h>

#define HDIM 64
#define EPSBN 1e-5f

// ---------------- degree count / dinv ----------------
__global__ void count_edges_k(const int* __restrict__ col, int* __restrict__ cnt, int E) {
    int e = blockIdx.x * blockDim.x + threadIdx.x;
    if (e < E) atomicAdd(&cnt[col[e]], 1);
}

__global__ void dinv_k(const int* __restrict__ cnt, float* __restrict__ dinv, int n) {
    int i = blockIdx.x * blockDim.x + threadIdx.x;
    if (i < n) dinv[i] = rsqrtf((float)cnt[i] + 1.0f);   // +1 for self-loop
}

// ---------------- exclusive scan of cnt -> offs (3-phase) ----------------
// phase 1: per-block (1024 elems) local exclusive scan + block total
__global__ void scan_partial_k(const int* __restrict__ cnt, int* __restrict__ offs,
                               int* __restrict__ bsum, int n) {
    __shared__ int lds[256];
    int tid = threadIdx.x;
    int base = blockIdx.x * 1024 + tid * 4;
    int v0 = (base + 0 < n) ? cnt[base + 0] : 0;
    int v1 = (base + 1 < n) ? cnt[base + 1] : 0;
    int v2 = (base + 2 < n) ? cnt[base + 2] : 0;
    int v3 = (base + 3 < n) ? cnt[base + 3] : 0;
    int tsum = v0 + v1 + v2 + v3;
    lds[tid] = tsum;
    __syncthreads();
    for (int off = 1; off < 256; off <<= 1) {
        int t = (tid >= off) ? lds[tid - off] : 0;
        __syncthreads();
        lds[tid] += t;
        __syncthreads();
    }
    int excl = lds[tid] - tsum;
    if (tid == 255) bsum[blockIdx.x] = lds[255];
    int run = excl;
    if (base + 0 < n) { offs[base + 0] = run; } run += v0;
    if (base + 1 < n) { offs[base + 1] = run; } run += v1;
    if (base + 2 < n) { offs[base + 2] = run; } run += v2;
    if (base + 3 < n) { offs[base + 3] = run; }
}

// phase 2: scan block sums (single block, supports nb <= 256)
__global__ void scan_roots_k(int* __restrict__ bsum, int nb) {
    __shared__ int lds[256];
    int tid = threadIdx.x;
    int v = (tid < nb) ? bsum[tid] : 0;
    lds[tid] = v;
    __syncthreads();
    for (int off = 1; off < 256; off <<= 1) {
        int t = (tid >= off) ? lds[tid - off] : 0;
        __syncthreads();
        lds[tid] += t;
        __syncthreads();
    }
    if (tid < nb) bsum[tid] = lds[tid] - v;   // exclusive
}

// phase 3: add block bases; init cursor; write offs[n]
__global__ void scan_add_k(int* __restrict__ offs, const int* __restrict__ bsum,
                           int* __restrict__ cursor, int n, int Etot) {
    int i = blockIdx.x * blockDim.x + threadIdx.x;
    if (i < n) {
        int o = offs[i] + bsum[i >> 10];
        offs[i] = o;
        cursor[i] = o;
    }
    if (i == 0) offs[n] = Etot;
}

// ---------------- CSR fill: per target node, list of (src, norm) ----------------
__global__ void fill_csr_k(const int* __restrict__ row, const int* __restrict__ col,
                           const float* __restrict__ dinv, int* __restrict__ cursor,
                           int2* __restrict__ srcw, int E) {
    int e = blockIdx.x * blockDim.x + threadIdx.x;
    if (e >= E) return;
    int r = row[e], c = col[e];
    float w = dinv[r] * dinv[c];
    int pos = atomicAdd(&cursor[c], 1);
    srcw[pos] = make_int2(r, __float_as_int(w));
}

// ---------------- dense transform: ht = hin @ W  (KIN -> 64) ----------------
// one 64-thread block handles 8 nodes; lane = output feature; W column in VGPRs
template <int KIN>
__global__ __launch_bounds__(64) void transform_k(const float* __restrict__ hin,
                                                  const float* __restrict__ W,
                                                  float* __restrict__ ht, int n) {
    int lane = threadIdx.x;
    float wreg[KIN];
#pragma unroll
    for (int k = 0; k < KIN; k++) wreg[k] = W[k * HDIM + lane];
    int i0 = blockIdx.x * 8;
    for (int j = 0; j < 8; j++) {
        int i = i0 + j;
        if (i >= n) return;
        const float* rowp = hin + (size_t)i * KIN;   // wave-uniform address -> s_load
        float acc = 0.f;
#pragma unroll
        for (int k = 0; k < KIN; k++) acc = fmaf(rowp[k], wreg[k], acc);
        ht[(size_t)i * HDIM + lane] = acc;
    }
}

// ---------------- aggregate + bias + BN + ReLU ----------------
// one block (1 wave) per node; lane = feature; CSR gather, no atomics
__global__ __launch_bounds__(64) void aggregate_k(
    const float* __restrict__ ht, const int* __restrict__ offs,
    const int2* __restrict__ srcw, const float* __restrict__ dinv,
    const float* __restrict__ bias, const float* __restrict__ g,
    const float* __restrict__ bshift, const float* __restrict__ m,
    const float* __restrict__ v, float* __restrict__ hout, int n) {
    int i = blockIdx.x;
    if (i >= n) return;
    int f = threadIdx.x;
    float di = dinv[i];
    float acc = ht[(size_t)i * HDIM + f] * (di * di);    // self-loop
    int s0 = offs[i], s1 = offs[i + 1];
    for (int e = s0; e < s1; e++) {
        int2 sw = srcw[e];                                // uniform -> s_load
        acc = fmaf(__int_as_float(sw.y), ht[(size_t)sw.x * HDIM + f], acc);
    }
    float sc = g[f] * rsqrtf(v[f] + EPSBN);
    float sh = (bias[f] - m[f]) * sc + bshift[f];
    float r = fmaf(acc, sc, sh);
    hout[(size_t)i * HDIM + f] = fmaxf(r, 0.f);
}

// ---------------- pooling (mean+max over sorted batch) + 2-layer MLP ----------------
__global__ __launch_bounds__(64) void pool_mlp_k(
    const float* __restrict__ h, const int* __restrict__ batch,
    const float* __restrict__ Wc1, const float* __restrict__ bc1,
    const float* __restrict__ Wc2, const float* __restrict__ bc2,
    float* __restrict__ out, int n) {
    int gidx = blockIdx.x;
    int lane = threadIdx.x;
    // binary search segment [start, end) in sorted batch
    int lo = 0, hi = n;
    while (lo < hi) { int mid = (lo + hi) >> 1; if (batch[mid] < gidx) lo = mid + 1; else hi = mid; }
    int start = lo;
    lo = start; hi = n;
    while (lo < hi) { int mid = (lo + hi) >> 1; if (batch[mid] < gidx + 1) lo = mid + 1; else hi = mid; }
    int end = lo;

    float sum = 0.f, mx = 0.f;   // h >= 0 post-ReLU, graphs non-empty
    for (int i = start; i < end; i++) {
        float val = h[(size_t)i * HDIM + lane];
        sum += val;
        mx = fmaxf(mx, val);
    }
    int cnt = end - start;
    float mean = sum / fmaxf((float)cnt, 1.f);

    __shared__ float pooled[2 * HDIM];
    pooled[lane] = mean;
    pooled[HDIM + lane] = mx;
    __syncthreads();

    float a = bc1[lane];
#pragma unroll
    for (int k = 0; k < 2 * HDIM; k++) a = fmaf(pooled[k], Wc1[k * HDIM + lane], a);
    a = fmaxf(a, 0.f);

#pragma unroll
    for (int c = 0; c < 2; c++) {
        float vv = a * Wc2[lane * 2 + c];
        for (int off = 32; off; off >>= 1) vv += __shfl_down(vv, off);
        if (lane == 0) out[gidx * 2 + c] = vv + bc2[c];
    }
}

extern "C" void kernel_launch(void* const* d_in, const int* in_sizes, int n_in,
                              void* d_out, int out_size, void* d_ws, size_t ws_size,
                              hipStream_t stream) {
    const float* x    = (const float*)d_in[0];
    const int*   erow = (const int*)d_in[1];
    const int*   ecol = (const int*)d_in[2];
    const int*   batch= (const int*)d_in[3];
    const float* W0   = (const float*)d_in[4];
    const float* b0   = (const float*)d_in[5];
    const float* W1   = (const float*)d_in[6];
    const float* b1   = (const float*)d_in[7];
    const float* W2   = (const float*)d_in[8];
    const float* b2   = (const float*)d_in[9];
    const float* bn_g = (const float*)d_in[10];
    const float* bn_b = (const float*)d_in[11];
    const float* bn_m = (const float*)d_in[12];
    const float* bn_v = (const float*)d_in[13];
    const float* Wc1  = (const float*)d_in[14];
    const float* bc1  = (const float*)d_in[15];
    const float* Wc2  = (const float*)d_in[16];
    const float* bc2  = (const float*)d_in[17];
    float* out = (float*)d_out;

    const int N = in_sizes[3];          // batch vector length = nodes
    const int E = in_sizes[1];          // edges
    const int G = out_size / 2;         // graphs
    const int IN_DIM = in_sizes[0] / N; // 26

    // workspace layout
    char* ws = (char*)d_ws;
    size_t off = 0;
    auto alloc = [&](size_t bytes) -> void* {
        void* p = ws + off;
        off += (bytes + 255) & ~(size_t)255;
        return p;
    };
    int*   cnt    = (int*)alloc((size_t)N * 4);
    float* dinv   = (float*)alloc((size_t)N * 4);
    int*   offs   = (int*)alloc((size_t)(N + 1) * 4);
    int*   cursor = (int*)alloc((size_t)N * 4);
    int*   bsum   = (int*)alloc(1024);
    int2*  srcw   = (int2*)alloc((size_t)E * 8);
    float* bufA   = (float*)alloc((size_t)N * HDIM * 4);
    float* bufB   = (float*)alloc((size_t)N * HDIM * 4);
    (void)ws_size;

    // ---- build gcn_norm + CSR transpose ----
    hipMemsetAsync(cnt, 0, (size_t)N * 4, stream);
    count_edges_k<<<(E + 255) / 256, 256, 0, stream>>>(ecol, cnt, E);
    dinv_k<<<(N + 255) / 256, 256, 0, stream>>>(cnt, dinv, N);
    int nb = (N + 1023) / 1024;
    scan_partial_k<<<nb, 256, 0, stream>>>(cnt, offs, bsum, N);
    scan_roots_k<<<1, 256, 0, stream>>>(bsum, nb);
    scan_add_k<<<(N + 255) / 256, 256, 0, stream>>>(offs, bsum, cursor, N, E);
    fill_csr_k<<<(E + 255) / 256, 256, 0, stream>>>(erow, ecol, dinv, cursor, srcw, E);

    // ---- layer 0: x(26) -> A ----
    transform_k<26><<<(N + 7) / 8, 64, 0, stream>>>(x, W0, bufB, N);
    aggregate_k<<<N, 64, 0, stream>>>(bufB, offs, srcw, dinv,
                                      b0, bn_g + 0, bn_b + 0, bn_m + 0, bn_v + 0, bufA, N);
    // ---- layer 1 ----
    transform_k<64><<<(N + 7) / 8, 64, 0, stream>>>(bufA, W1, bufB, N);
    aggregate_k<<<N, 64, 0, stream>>>(bufB, offs, srcw, dinv,
                                      b1, bn_g + 64, bn_b + 64, bn_m + 64, bn_v + 64, bufA, N);
    // ---- layer 2 ----
    transform_k<64><<<(N + 7) / 8, 64, 0, stream>>>(bufA, W2, bufB, N);
    aggregate_k<<<N, 64, 0, stream>>>(bufB, offs, srcw, dinv,
                                      b2, bn_g + 128, bn_b + 128, bn_m + 128, bn_v + 128, bufA, N);

    // ---- pool + MLP ----
    pool_mlp_k<<<G, 64, 0, stream>>>(bufA, batch, Wc1, bc1, Wc2, bc2, out, N);
}

// Round 2
// 513.049 us; speedup vs baseline: 1.3224x; 1.3224x over previous
//
#include <hip/hip_runtime.h>

#define HDIM 64
#define EPSBN 1e-5f
#define MNODES 8

// ---------------- degree count / dinv ----------------
__global__ void count_edges_k(const int* __restrict__ col, int* __restrict__ cnt, int E) {
    int e = blockIdx.x * blockDim.x + threadIdx.x;
    if (e < E) atomicAdd(&cnt[col[e]], 1);
}

__global__ void dinv_k(const int* __restrict__ cnt, float* __restrict__ dinv, int n) {
    int i = blockIdx.x * blockDim.x + threadIdx.x;
    if (i < n) dinv[i] = rsqrtf((float)cnt[i] + 1.0f);   // +1 for self-loop
}

// ---------------- exclusive scan of cnt -> offs (3-phase) ----------------
__global__ void scan_partial_k(const int* __restrict__ cnt, int* __restrict__ offs,
                               int* __restrict__ bsum, int n) {
    __shared__ int lds[256];
    int tid = threadIdx.x;
    int base = blockIdx.x * 1024 + tid * 4;
    int v0 = (base + 0 < n) ? cnt[base + 0] : 0;
    int v1 = (base + 1 < n) ? cnt[base + 1] : 0;
    int v2 = (base + 2 < n) ? cnt[base + 2] : 0;
    int v3 = (base + 3 < n) ? cnt[base + 3] : 0;
    int tsum = v0 + v1 + v2 + v3;
    lds[tid] = tsum;
    __syncthreads();
    for (int off = 1; off < 256; off <<= 1) {
        int t = (tid >= off) ? lds[tid - off] : 0;
        __syncthreads();
        lds[tid] += t;
        __syncthreads();
    }
    int excl = lds[tid] - tsum;
    if (tid == 255) bsum[blockIdx.x] = lds[255];
    int run = excl;
    if (base + 0 < n) { offs[base + 0] = run; } run += v0;
    if (base + 1 < n) { offs[base + 1] = run; } run += v1;
    if (base + 2 < n) { offs[base + 2] = run; } run += v2;
    if (base + 3 < n) { offs[base + 3] = run; }
}

__global__ void scan_roots_k(int* __restrict__ bsum, int nb) {
    __shared__ int lds[256];
    int tid = threadIdx.x;
    int v = (tid < nb) ? bsum[tid] : 0;
    lds[tid] = v;
    __syncthreads();
    for (int off = 1; off < 256; off <<= 1) {
        int t = (tid >= off) ? lds[tid - off] : 0;
        __syncthreads();
        lds[tid] += t;
        __syncthreads();
    }
    if (tid < nb) bsum[tid] = lds[tid] - v;   // exclusive
}

__global__ void scan_add_k(int* __restrict__ offs, const int* __restrict__ bsum,
                           int* __restrict__ cursor, int n, int Etot) {
    int i = blockIdx.x * blockDim.x + threadIdx.x;
    if (i < n) {
        int o = offs[i] + bsum[i >> 10];
        offs[i] = o;
        cursor[i] = o;
    }
    if (i == 0) offs[n] = Etot;
}

// ---------------- CSR fill, XCD-ownership version ----------------
// Each 256-edge chunk is visited by 8 blocks (one per XCD via blockIdx%8).
// A block only writes edges whose target col falls in its XCD's node range,
// so each srcw cache line is produced entirely within one XCD's L2 ->
// full-line evictions instead of 8x write amplification.
__global__ void fill_csr_k(const int* __restrict__ row, const int* __restrict__ col,
                           const float* __restrict__ dinv, int* __restrict__ cursor,
                           int2* __restrict__ srcw, int E, int N) {
    int xcd = blockIdx.x & 7;
    int chunk = blockIdx.x >> 3;
    int e = chunk * 256 + threadIdx.x;
    if (e >= E) return;
    int c = col[e];
    int owner = (int)(((unsigned long long)c * 8ull) / (unsigned)N);
    if (owner != xcd) return;
    int r = row[e];
    float w = dinv[r] * dinv[c];
    int pos = atomicAdd(&cursor[c], 1);
    srcw[pos] = make_int2(r, __float_as_int(w));
}

// ---------------- fused conv: aggregate-first + dense + bias + BN + ReLU ----------------
// one 64-thread block (1 wave) handles MNODES nodes serially; lane = output feature.
// conv(h) = (segsum(norm*h) + dinv^2*h_self) @ W, then y = conv*sc + sh, ReLU.
template <int KIN>
__global__ __launch_bounds__(64) void conv_k(
    const float* __restrict__ hin, const int* __restrict__ offs,
    const int2* __restrict__ srcw, const float* __restrict__ dinv,
    const float* __restrict__ W, const float* __restrict__ bias,
    const float* __restrict__ g, const float* __restrict__ bb,
    const float* __restrict__ m, const float* __restrict__ v,
    float* __restrict__ hout, int n) {
    int lane = threadIdx.x;
    float wreg[KIN];                        // W column for this lane
#pragma unroll
    for (int k = 0; k < KIN; k++) wreg[k] = W[k * HDIM + lane];
    float sc = g[lane] * rsqrtf(v[lane] + EPSBN);
    float sh = (bias[lane] - m[lane]) * sc + bb[lane];

    __shared__ float agg[KIN];

    int i0 = blockIdx.x * MNODES;
    for (int j = 0; j < MNODES; j++) {
        int i = i0 + j;
        if (i >= n) break;                  // wave-uniform
        float di = dinv[i];
        float acc = 0.f;
        if (lane < KIN) acc = hin[(size_t)i * KIN + lane] * (di * di);  // self-loop
        int e = offs[i], s1 = offs[i + 1];
        for (; e + 4 <= s1; e += 4) {
            int2 sw0 = srcw[e], sw1 = srcw[e + 1], sw2 = srcw[e + 2], sw3 = srcw[e + 3];
            float h0 = 0.f, h1 = 0.f, h2 = 0.f, h3 = 0.f;
            if (lane < KIN) {
                h0 = hin[(size_t)sw0.x * KIN + lane];
                h1 = hin[(size_t)sw1.x * KIN + lane];
                h2 = hin[(size_t)sw2.x * KIN + lane];
                h3 = hin[(size_t)sw3.x * KIN + lane];
            }
            acc = fmaf(__int_as_float(sw0.y), h0, acc);
            acc = fmaf(__int_as_float(sw1.y), h1, acc);
            acc = fmaf(__int_as_float(sw2.y), h2, acc);
            acc = fmaf(__int_as_float(sw3.y), h3, acc);
        }
        for (; e < s1; e++) {
            int2 sw = srcw[e];
            float hh = (lane < KIN) ? hin[(size_t)sw.x * KIN + lane] : 0.f;
            acc = fmaf(__int_as_float(sw.y), hh, acc);
        }
        __syncthreads();                    // protect agg from previous iteration readers
        if (lane < KIN) agg[lane] = acc;
        __syncthreads();
        float dot = 0.f;
#pragma unroll
        for (int k = 0; k < KIN; k++) dot = fmaf(agg[k], wreg[k], dot);  // agg[k] broadcast
        float y = fmaf(dot, sc, sh);
        hout[(size_t)i * HDIM + lane] = fmaxf(y, 0.f);
    }
}

// ---------------- pooling (4 waves per graph) + 2-layer MLP ----------------
__global__ __launch_bounds__(256) void pool_mlp_k(
    const float* __restrict__ h, const int* __restrict__ batch,
    const float* __restrict__ Wc1, const float* __restrict__ bc1,
    const float* __restrict__ Wc2, const float* __restrict__ bc2,
    float* __restrict__ out, int n) {
    int gidx = blockIdx.x;
    int tid = threadIdx.x;
    int lane = tid & 63;
    int wv = tid >> 6;

    // binary search segment [start, end) in sorted batch
    int lo = 0, hi = n;
    while (lo < hi) { int mid = (lo + hi) >> 1; if (batch[mid] < gidx) lo = mid + 1; else hi = mid; }
    int start = lo;
    lo = start; hi = n;
    while (lo < hi) { int mid = (lo + hi) >> 1; if (batch[mid] <= gidx) lo = mid + 1; else hi = mid; }
    int end = lo;

    float sum = 0.f, mx = 0.f;   // h >= 0 post-ReLU, graphs non-empty
    for (int i = start + wv; i < end; i += 4) {
        float val = h[(size_t)i * HDIM + lane];
        sum += val;
        mx = fmaxf(mx, val);
    }
    __shared__ float ssum[4 * HDIM];
    __shared__ float smax[4 * HDIM];
    __shared__ float pooled[2 * HDIM];
    ssum[wv * HDIM + lane] = sum;
    smax[wv * HDIM + lane] = mx;
    __syncthreads();
    if (wv == 0) {
        float s = ssum[lane] + ssum[64 + lane] + ssum[128 + lane] + ssum[192 + lane];
        float mm = fmaxf(fmaxf(smax[lane], smax[64 + lane]),
                         fmaxf(smax[128 + lane], smax[192 + lane]));
        int cnt = end - start;
        pooled[lane] = s / fmaxf((float)cnt, 1.f);
        pooled[HDIM + lane] = mm;
    }
    __syncthreads();
    if (wv == 0) {
        float a = bc1[lane];
#pragma unroll
        for (int k = 0; k < 2 * HDIM; k++) a = fmaf(pooled[k], Wc1[k * HDIM + lane], a);
        a = fmaxf(a, 0.f);
#pragma unroll
        for (int c = 0; c < 2; c++) {
            float vv = a * Wc2[lane * 2 + c];
            for (int off = 32; off; off >>= 1) vv += __shfl_down(vv, off);
            if (lane == 0) out[gidx * 2 + c] = vv + bc2[c];
        }
    }
}

extern "C" void kernel_launch(void* const* d_in, const int* in_sizes, int n_in,
                              void* d_out, int out_size, void* d_ws, size_t ws_size,
                              hipStream_t stream) {
    const float* x    = (const float*)d_in[0];
    const int*   erow = (const int*)d_in[1];
    const int*   ecol = (const int*)d_in[2];
    const int*   batch= (const int*)d_in[3];
    const float* W0   = (const float*)d_in[4];
    const float* b0   = (const float*)d_in[5];
    const float* W1   = (const float*)d_in[6];
    const float* b1   = (const float*)d_in[7];
    const float* W2   = (const float*)d_in[8];
    const float* b2   = (const float*)d_in[9];
    const float* bn_g = (const float*)d_in[10];
    const float* bn_b = (const float*)d_in[11];
    const float* bn_m = (const float*)d_in[12];
    const float* bn_v = (const float*)d_in[13];
    const float* Wc1  = (const float*)d_in[14];
    const float* bc1  = (const float*)d_in[15];
    const float* Wc2  = (const float*)d_in[16];
    const float* bc2  = (const float*)d_in[17];
    float* out = (float*)d_out;

    const int N = in_sizes[3];          // nodes
    const int E = in_sizes[1];          // edges
    const int G = out_size / 2;         // graphs

    // workspace layout
    char* ws = (char*)d_ws;
    size_t off = 0;
    auto alloc = [&](size_t bytes) -> void* {
        void* p = ws + off;
        off += (bytes + 255) & ~(size_t)255;
        return p;
    };
    int*   cnt    = (int*)alloc((size_t)N * 4);
    float* dinv   = (float*)alloc((size_t)N * 4);
    int*   offs   = (int*)alloc((size_t)(N + 1) * 4);
    int*   cursor = (int*)alloc((size_t)N * 4);
    int*   bsum   = (int*)alloc(1024);
    int2*  srcw   = (int2*)alloc((size_t)E * 8);
    float* bufA   = (float*)alloc((size_t)N * HDIM * 4);
    float* bufB   = (float*)alloc((size_t)N * HDIM * 4);
    (void)ws_size;

    // ---- build gcn_norm + CSR transpose ----
    hipMemsetAsync(cnt, 0, (size_t)N * 4, stream);
    count_edges_k<<<(E + 255) / 256, 256, 0, stream>>>(ecol, cnt, E);
    dinv_k<<<(N + 255) / 256, 256, 0, stream>>>(cnt, dinv, N);
    int nb = (N + 1023) / 1024;
    scan_partial_k<<<nb, 256, 0, stream>>>(cnt, offs, bsum, N);
    scan_roots_k<<<1, 256, 0, stream>>>(bsum, nb);
    scan_add_k<<<(N + 255) / 256, 256, 0, stream>>>(offs, bsum, cursor, N, E);
    int chunks = (E + 255) / 256;
    fill_csr_k<<<chunks * 8, 256, 0, stream>>>(erow, ecol, dinv, cursor, srcw, E, N);

    int cgrid = (N + MNODES - 1) / MNODES;
    // ---- layer 0: aggregate x (26) then dense 26->64, BN+ReLU ----
    conv_k<26><<<cgrid, 64, 0, stream>>>(x, offs, srcw, dinv, W0, b0,
                                         bn_g + 0, bn_b + 0, bn_m + 0, bn_v + 0, bufA, N);
    // ---- layer 1 ----
    conv_k<64><<<cgrid, 64, 0, stream>>>(bufA, offs, srcw, dinv, W1, b1,
                                         bn_g + 64, bn_b + 64, bn_m + 64, bn_v + 64, bufB, N);
    // ---- layer 2 ----
    conv_k<64><<<cgrid, 64, 0, stream>>>(bufB, offs, srcw, dinv, W2, b2,
                                         bn_g + 128, bn_b + 128, bn_m + 128, bn_v + 128, bufA, N);

    // ---- pool + MLP ----
    pool_mlp_k<<<G, 256, 0, stream>>>(bufA, batch, Wc1, bc1, Wc2, bc2, out, N);
}